// Round 1
// baseline (774.607 us; speedup 1.0000x reference)
//
#include <hip/hip_runtime.h>
#include <hip/hip_bf16.h>

// Problem constants (REN forward)
#define N_X 64
#define N_UNITS 256
#define N_Y 32
#define N_U 64
#define NZ 384  // 2*N_X + N_UNITS

// ---------------------------------------------------------------------------
// Prep 1: lT1 (384x64), lT2 (384x32), t1 = lT1 @ Rinv (384x64),
//         t2 = lT2 @ Q (384x32).  One block per row r, 64 threads.
// ---------------------------------------------------------------------------
__global__ __launch_bounds__(64) void ren_prep1(
    const float* __restrict__ B2, const float* __restrict__ C2,
    const float* __restrict__ D12, const float* __restrict__ D21,
    const float* __restrict__ St, const float* __restrict__ Q,
    const float* __restrict__ Rinv,
    float* __restrict__ lT1, float* __restrict__ t1,
    float* __restrict__ lT2, float* __restrict__ t2)
{
    __shared__ float s1[64];
    __shared__ float s2[32];
    const int r = blockIdx.x;   // 0..383
    const int c = threadIdx.x;  // 0..63

    // lT1[r][c]
    float v1;
    if (r < 64) {
        // C2_.T where C2_ = St @ C2  -> lT1[r][c] = sum_p St[c][p]*C2[p][r]
        float s = 0.f;
        for (int p = 0; p < 32; p++) s += St[c * 32 + p] * C2[p * 64 + r];
        v1 = s;
    } else if (r < 320) {
        // D21_.T where D21_ = St @ D21 - D12.T
        const int j = r - 64;
        float s = 0.f;
        for (int p = 0; p < 32; p++) s += St[c * 32 + p] * D21[p * 256 + j];
        v1 = s - D12[j * 64 + c];
    } else {
        v1 = B2[(r - 320) * 64 + c];
    }
    s1[c] = v1;
    lT1[r * 64 + c] = v1;

    if (c < 32) {
        float v2;
        if (r < 64)       v2 = C2[c * 64 + r];          // C2.T
        else if (r < 320) v2 = D21[c * 256 + (r - 64)]; // D21.T
        else              v2 = 0.f;
        s2[c] = v2;
        lT2[r * 32 + c] = v2;
    }
    __syncthreads();

    // t1[r][c] = sum_k lT1[r][k] * Rinv[k][c]
    float a = 0.f;
    for (int k = 0; k < 64; k++) a += s1[k] * Rinv[k * 64 + c];
    t1[r * 64 + c] = a;

    if (c < 32) {
        float bq = 0.f;
        for (int k = 0; k < 32; k++) bq += s2[k] * Q[k * 32 + c];
        t2[r * 32 + c] = bq;
    }
}

// ---------------------------------------------------------------------------
// Prep 2: H rows 64..319, cols 0..319:
//   H[r][c] = sum_k X[k][r]*X[k][c] + 0.001*(r==c)
//           + sum_m t1[r][m]*lT1[c][m] - sum_m t2[r][m]*lT2[c][m]
// Emit: C1[i][c] = -H[64+i][c] (c<64)
//       Drows[i+1][cb] = -(cb<=i-1 ? H22[i][cb] : 0), Drows[0][*]=0
//       laminv[i] = 2 / H22[i][i]
// Grid: 64 blocks x 320 threads; each block does 4 H-rows.
// ---------------------------------------------------------------------------
__global__ __launch_bounds__(320) void ren_prep2(
    const float* __restrict__ X,
    const float* __restrict__ lT1, const float* __restrict__ t1,
    const float* __restrict__ lT2, const float* __restrict__ t2,
    float* __restrict__ C1, float* __restrict__ Drows,
    float* __restrict__ laminv)
{
    const int c = threadIdx.x;        // 0..319 (H column)
    const int rb = blockIdx.x * 4;    // row block within [0,256)

    float acc[4];
#pragma unroll
    for (int q = 0; q < 4; q++) acc[q] = ((64 + rb + q) == c) ? 0.001f : 0.f;

    // X.T @ X part: vector load X[k][c] (coalesced), scalar X[k][64+rb+q]
    for (int k = 0; k < 384; k++) {
        const float xc = X[k * 384 + c];
#pragma unroll
        for (int q = 0; q < 4; q++)
            acc[q] += X[k * 384 + 64 + rb + q] * xc;
    }

    // + t1-row . lT1[c]  - t2-row . lT2[c]
#pragma unroll
    for (int q = 0; q < 4; q++) {
        const int r = 64 + rb + q;
        float a = 0.f;
        for (int m = 0; m < 64; m++) a += t1[r * 64 + m] * lT1[c * 64 + m];
        float bq = 0.f;
        for (int m = 0; m < 32; m++) bq += t2[r * 32 + m] * lT2[c * 32 + m];
        acc[q] += a - bq;
    }

#pragma unroll
    for (int q = 0; q < 4; q++) {
        const int i = rb + q;       // row within H_21/H_22 block
        const float h = acc[q];
        if (c < 64) {
            C1[i * 64 + c] = -h;    // C_1 = -H_21
        } else {
            const int cb = c - 64;
            if (cb == i) laminv[i] = 2.0f / h;   // 1/lam
            if (i < 255)
                Drows[(i + 1) * 256 + cb] = (cb <= i - 1) ? -h : 0.f;
            else
                Drows[cb] = 0.f;    // Drows row 0 = zeros
        }
    }
}

// ---------------------------------------------------------------------------
// Main: thread-per-batch-element. w[256] in LDS (XOR-swizzled float4 chunks,
// conflict-free b128). All weights via wave-uniform scalar loads.
// ---------------------------------------------------------------------------
__global__ __launch_bounds__(64) void ren_main(
    const float* __restrict__ u, const float* __restrict__ x0,
    const float* __restrict__ b, const float* __restrict__ C2,
    const float* __restrict__ D12, const float* __restrict__ D21,
    const float* __restrict__ C1, const float* __restrict__ Drows,
    const float* __restrict__ laminv, float* __restrict__ out)
{
    __shared__ float4 wsh[64][64];  // exactly 64 KiB: [thread][chunk of 4 w's]
    const int t = threadIdx.x;
    const int swz = t & 7;
    const long row = (long)blockIdx.x * 64 + t;

    // Load this element's x and u rows into registers (16B per lane).
    const float* __restrict__ xrow = x0 + row * 64;
    const float* __restrict__ urow = u + row * 64;
    float x2[64], u2[64];
#pragma unroll
    for (int k = 0; k < 64; k += 4) {
        const float4 xv = *(const float4*)(xrow + k);
        x2[k] = xv.x; x2[k + 1] = xv.y; x2[k + 2] = xv.z; x2[k + 3] = xv.w;
        const float4 uv = *(const float4*)(urow + k);
        u2[k] = uv.x; u2[k + 1] = uv.y; u2[k + 2] = uv.z; u2[k + 3] = uv.w;
    }

    // ---- v phase: v[i] = b_w[i] + C1[i,:].x2 + D12[i,:].u2  (into LDS) ----
    const float* __restrict__ bw = b + 64;
    for (int i0 = 0; i0 < 256; i0 += 4) {
        const float* __restrict__ c0 = C1 + i0 * 64;
        const float* __restrict__ d0 = D12 + i0 * 64;
        float a0 = bw[i0], a1 = bw[i0 + 1], a2 = bw[i0 + 2], a3 = bw[i0 + 3];
#pragma unroll
        for (int k = 0; k < 64; k++) {
            a0 += c0[k] * x2[k];
            a1 += c0[64 + k] * x2[k];
            a2 += c0[128 + k] * x2[k];
            a3 += c0[192 + k] * x2[k];
        }
#pragma unroll
        for (int k = 0; k < 64; k++) {
            a0 += d0[k] * u2[k];
            a1 += d0[64 + k] * u2[k];
            a2 += d0[128 + k] * u2[k];
            a3 += d0[192 + k] * u2[k];
        }
        wsh[t][(i0 >> 2) ^ swz] = make_float4(a0, a1, a2, a3);
    }

    // ---- recurrence: w_i = tanh((v_i + sum_{j<=i-2} d_ij w_j) / lam_i) ----
    // i-blocked by 8: dense history from LDS (stored zeros handle edges),
    // in-block triangle from registers.
    for (int i0 = 0; i0 < 256; i0 += 8) {
        const float4 v0 = wsh[t][(i0 >> 2) ^ swz];
        const float4 v1 = wsh[t][((i0 >> 2) + 1) ^ swz];
        float acc[8] = {v0.x, v0.y, v0.z, v0.w, v1.x, v1.y, v1.z, v1.w};
        const float* __restrict__ dr = Drows + i0 * 256;
        const int jcmax = i0 >> 2;
        for (int jc = 0; jc < jcmax; jc++) {
            const float4 wv = wsh[t][jc ^ swz];
            const int j = jc * 4;
#pragma unroll
            for (int q = 0; q < 4; q++) {
                const float wj = (q == 0) ? wv.x : (q == 1) ? wv.y
                                : (q == 2) ? wv.z : wv.w;
#pragma unroll
                for (int r8 = 0; r8 < 8; r8++)
                    acc[r8] += dr[r8 * 256 + j + q] * wj;
            }
        }
        float wblk[8];
#pragma unroll
        for (int q = 0; q < 8; q++) {
            float a = acc[q];
            const float* __restrict__ dri = Drows + (i0 + q) * 256 + i0;
#pragma unroll
            for (int p = 0; p <= q - 2; p++) a += dri[p] * wblk[p];
            a *= laminv[i0 + q];
            a = fminf(fmaxf(a, -15.f), 15.f);
            const float e = __expf(2.f * a);
            wblk[q] = (e - 1.f) * __builtin_amdgcn_rcpf(e + 1.f);
        }
        wsh[t][(i0 >> 2) ^ swz] = make_float4(wblk[0], wblk[1], wblk[2], wblk[3]);
        wsh[t][((i0 >> 2) + 1) ^ swz] = make_float4(wblk[4], wblk[5], wblk[6], wblk[7]);
    }

    // ---- y phase: y = C2.x2 + D21.w + b_y ----
    float y[32];
    const float* __restrict__ by = b + 320;
#pragma unroll
    for (int o = 0; o < 32; o++) y[o] = by[o];
#pragma unroll
    for (int k = 0; k < 64; k++) {
        const float xk = x2[k];
#pragma unroll
        for (int o = 0; o < 32; o++) y[o] += C2[o * 64 + k] * xk;
    }
    for (int jc = 0; jc < 64; jc++) {
        const float4 wv = wsh[t][jc ^ swz];
        const int j = jc * 4;
#pragma unroll
        for (int q = 0; q < 4; q++) {
            const float wj = (q == 0) ? wv.x : (q == 1) ? wv.y
                            : (q == 2) ? wv.z : wv.w;
#pragma unroll
            for (int o = 0; o < 32; o++) y[o] += D21[o * 256 + j + q] * wj;
        }
    }
    float4* __restrict__ orow = (float4*)(out + row * 32);
#pragma unroll
    for (int o = 0; o < 32; o += 4)
        orow[o >> 2] = make_float4(y[o], y[o + 1], y[o + 2], y[o + 3]);
}

// ---------------------------------------------------------------------------
extern "C" void kernel_launch(void* const* d_in, const int* in_sizes, int n_in,
                              void* d_out, int out_size, void* d_ws, size_t ws_size,
                              hipStream_t stream)
{
    const float* u    = (const float*)d_in[0];
    const float* x0   = (const float*)d_in[1];
    const float* B2   = (const float*)d_in[2];
    const float* C2   = (const float*)d_in[3];
    const float* D12  = (const float*)d_in[4];
    const float* D21  = (const float*)d_in[5];
    const float* b    = (const float*)d_in[6];
    const float* X    = (const float*)d_in[7];
    // d_in[8] = Y1 (unused in forward)
    const float* St   = (const float*)d_in[9];
    const float* Q    = (const float*)d_in[10];
    const float* Rinv = (const float*)d_in[11];
    float* out = (float*)d_out;

    // Workspace layout (floats). Total ~624 KB.
    float* ws     = (float*)d_ws;
    float* lT1    = ws;                    // 384*64
    float* t1     = lT1 + 384 * 64;        // 384*64
    float* lT2    = t1 + 384 * 64;         // 384*32
    float* t2     = lT2 + 384 * 32;        // 384*32
    float* C1w    = t2 + 384 * 32;         // 256*64
    float* Drows  = C1w + 256 * 64;        // 256*256
    float* laminv = Drows + 256 * 256;     // 256

    ren_prep1<<<dim3(384), dim3(64), 0, stream>>>(B2, C2, D12, D21, St, Q, Rinv,
                                                  lT1, t1, lT2, t2);
    ren_prep2<<<dim3(64), dim3(320), 0, stream>>>(X, lT1, t1, lT2, t2,
                                                  C1w, Drows, laminv);
    const int batch = in_sizes[0] / 64;  // 32768
    ren_main<<<dim3(batch / 64), dim3(64), 0, stream>>>(u, x0, b, C2, D12, D21,
                                                        C1w, Drows, laminv, out);
}

// Round 2
// 166.616 us; speedup vs baseline: 4.6491x; 4.6491x over previous
//
#include <hip/hip_runtime.h>
#include <hip/hip_bf16.h>

// REN forward: BATCH=32768, N_X=64, N_UNITS=256, N_Y=32, N_U=64
typedef __attribute__((ext_vector_type(8))) short short8;
typedef __attribute__((ext_vector_type(4))) float floatx4;

__device__ inline unsigned short bf16_rne(float f) {
    unsigned int u = __float_as_uint(f);
    unsigned int r = (u + 0x7fffu + ((u >> 16) & 1u)) >> 16;
    return (unsigned short)r;
}
__device__ inline float bf16_to_f(unsigned short s) {
    return __uint_as_float(((unsigned int)s) << 16);
}
__device__ inline short8 pack8(float4 a, float4 b) {
    short8 r;
    r[0] = (short)bf16_rne(a.x); r[1] = (short)bf16_rne(a.y);
    r[2] = (short)bf16_rne(a.z); r[3] = (short)bf16_rne(a.w);
    r[4] = (short)bf16_rne(b.x); r[5] = (short)bf16_rne(b.y);
    r[6] = (short)bf16_rne(b.z); r[7] = (short)bf16_rne(b.w);
    return r;
}

// ---------------------------------------------------------------------------
// Prep 1: lT1 (384x64), lT2 (384x32), t1 = lT1@Rinv, t2 = lT2@Q.
// ---------------------------------------------------------------------------
__global__ __launch_bounds__(64) void ren_prep1(
    const float* __restrict__ B2, const float* __restrict__ C2,
    const float* __restrict__ D12, const float* __restrict__ D21,
    const float* __restrict__ St, const float* __restrict__ Q,
    const float* __restrict__ Rinv,
    float* __restrict__ lT1, float* __restrict__ t1,
    float* __restrict__ lT2, float* __restrict__ t2)
{
    __shared__ float s1[64];
    __shared__ float s2[32];
    const int r = blockIdx.x;   // 0..383
    const int c = threadIdx.x;  // 0..63

    float v1;
    if (r < 64) {
        float s = 0.f;
        for (int p = 0; p < 32; p++) s += St[c * 32 + p] * C2[p * 64 + r];
        v1 = s;
    } else if (r < 320) {
        const int j = r - 64;
        float s = 0.f;
        for (int p = 0; p < 32; p++) s += St[c * 32 + p] * D21[p * 256 + j];
        v1 = s - D12[j * 64 + c];
    } else {
        v1 = B2[(r - 320) * 64 + c];
    }
    s1[c] = v1;
    lT1[r * 64 + c] = v1;

    if (c < 32) {
        float v2;
        if (r < 64)       v2 = C2[c * 64 + r];
        else if (r < 320) v2 = D21[c * 256 + (r - 64)];
        else              v2 = 0.f;
        s2[c] = v2;
        lT2[r * 32 + c] = v2;
    }
    __syncthreads();

    float a = 0.f;
    for (int k = 0; k < 64; k++) a += s1[k] * Rinv[k * 64 + c];
    t1[r * 64 + c] = a;

    if (c < 32) {
        float bq = 0.f;
        for (int k = 0; k < 32; k++) bq += s2[k] * Q[k * 32 + c];
        t2[r * 32 + c] = bq;
    }
}

// ---------------------------------------------------------------------------
// Prep 2: H rows 64..319 -> Wvb (C1 part, bf16), Drowsb (bf16, stored zeros
// above the -1 subdiagonal), laminv = 2/diag(H22).
// ---------------------------------------------------------------------------
__global__ __launch_bounds__(320) void ren_prep2(
    const float* __restrict__ X,
    const float* __restrict__ lT1, const float* __restrict__ t1,
    const float* __restrict__ lT2, const float* __restrict__ t2,
    unsigned short* __restrict__ Wvb, unsigned short* __restrict__ Drowsb,
    float* __restrict__ laminv)
{
    const int c = threadIdx.x;        // 0..319 (H column)
    const int rb = blockIdx.x * 4;    // row block within [0,256)

    float acc[4];
#pragma unroll
    for (int q = 0; q < 4; q++) acc[q] = ((64 + rb + q) == c) ? 0.001f : 0.f;

    for (int k = 0; k < 384; k++) {
        const float xc = X[k * 384 + c];
#pragma unroll
        for (int q = 0; q < 4; q++)
            acc[q] += X[k * 384 + 64 + rb + q] * xc;
    }

#pragma unroll
    for (int q = 0; q < 4; q++) {
        const int r = 64 + rb + q;
        float a = 0.f;
        for (int m = 0; m < 64; m++) a += t1[r * 64 + m] * lT1[c * 64 + m];
        float bq = 0.f;
        for (int m = 0; m < 32; m++) bq += t2[r * 32 + m] * lT2[c * 32 + m];
        acc[q] += a - bq;
    }

#pragma unroll
    for (int q = 0; q < 4; q++) {
        const int i = rb + q;
        const float h = acc[q];
        if (c < 64) {
            Wvb[i * 128 + c] = bf16_rne(-h);     // C_1 = -H_21 (bf16)
        } else {
            const int cb = c - 64;
            if (cb == i) laminv[i] = 2.0f / h;
            if (i < 255)
                Drowsb[(i + 1) * 256 + cb] = bf16_rne((cb <= i - 1) ? -h : 0.f);
            else
                Drowsb[cb] = 0;                  // Drows row 0 = zeros
        }
    }
}

// ---------------------------------------------------------------------------
// Prep 3: bf16 copies of D12 (Wvb cols 64..127), C2, D21.
// ---------------------------------------------------------------------------
__global__ __launch_bounds__(256) void ren_prep3(
    const float* __restrict__ D12, const float* __restrict__ C2,
    const float* __restrict__ D21,
    unsigned short* __restrict__ Wvb, unsigned short* __restrict__ C2b,
    unsigned short* __restrict__ D21b)
{
    const int id = blockIdx.x * 256 + threadIdx.x;
    if (id < 16384) {
        const int i = id >> 6, k = id & 63;
        Wvb[i * 128 + 64 + k] = bf16_rne(D12[id]);
    } else if (id < 16384 + 2048) {
        const int j = id - 16384;
        C2b[j] = bf16_rne(C2[j]);
    } else if (id < 16384 + 2048 + 8192) {
        const int j = id - 16384 - 2048;
        D21b[j] = bf16_rne(D21[j]);
    }
}

// ---------------------------------------------------------------------------
// Main: one wave (64 threads) per 16 batch rows. All GEMM-shaped work via
// mfma_f32_16x16x32_bf16; only the in-block 16x16 triangle + tanh is scalar
// (16 lanes, one per batch row), transposed through LDS.
//
// MFMA 16x16x32 layouts (gfx950, learn_hip m89/m120):
//   A: lane holds A[m=lane&15][k=(lane>>4)*8 + j], j=0..7
//   B: lane holds B[k=(lane>>4)*8 + j][n=lane&15]
//   C/D: lane holds D[row=(lane>>4)*4 + r][col=lane&15], r=0..3
// ---------------------------------------------------------------------------
__global__ __launch_bounds__(64) void ren_main(
    const float* __restrict__ u, const float* __restrict__ x0,
    const float* __restrict__ b,
    const unsigned short* __restrict__ Wvb,
    const unsigned short* __restrict__ Drowsb,
    const float* __restrict__ laminv,
    const unsigned short* __restrict__ C2b,
    const unsigned short* __restrict__ D21b,
    float* __restrict__ out)
{
    __shared__ float buf[16][20];   // v / w transpose buffer (stride 20: <=2-way)
    __shared__ float dblk[16][16];  // in-block D tile (reads are broadcasts)

    const int L = threadIdx.x;
    const int col = L & 15;
    const int quad = L >> 4;
    const int row0 = blockIdx.x * 16;

    // z A-frags: 4 K-chunks of 32 over [x0 | u] for row m=col
    short8 zf[4];
#pragma unroll
    for (int c = 0; c < 4; c++) {
        const float* p = (c < 2 ? x0 : u) + (row0 + col) * 64 + (c & 1) * 32 + quad * 8;
        float4 lo = *(const float4*)p;
        float4 hi = *(const float4*)(p + 4);
        zf[c] = pack8(lo, hi);
    }

    short8 zero8 = {0, 0, 0, 0, 0, 0, 0, 0};
    short8 wf[8];
#pragma unroll
    for (int c = 0; c < 8; c++) wf[c] = zero8;

#pragma unroll
    for (int n = 0; n < 16; n++) {
        // ---- stage in-block D tile (bf16 -> fp32) into LDS ----
        {
            const unsigned short* ds =
                Drowsb + (16 * n + (L >> 2)) * 256 + 16 * n + (L & 3) * 4;
            const unsigned long long dv = *(const unsigned long long*)ds;
            float4 df;
            df.x = bf16_to_f((unsigned short)(dv       & 0xffff));
            df.y = bf16_to_f((unsigned short)((dv >> 16) & 0xffff));
            df.z = bf16_to_f((unsigned short)((dv >> 32) & 0xffff));
            df.w = bf16_to_f((unsigned short)((dv >> 48) & 0xffff));
            *(float4*)&dblk[L >> 2][(L & 3) * 4] = df;
        }

        // ---- v GEMM for this unit block: acc[16 rows][16 units] ----
        floatx4 acc = {0.f, 0.f, 0.f, 0.f};
#pragma unroll
        for (int c = 0; c < 4; c++) {
            short8 bfr = *(const short8*)(Wvb + (16 * n + col) * 128 + c * 32 + quad * 8);
            acc = __builtin_amdgcn_mfma_f32_16x16x32_bf16(zf[c], bfr, acc, 0, 0, 0);
        }
        // ---- dense history: j < 16n (stored zeros trim the boundary) ----
#pragma unroll
        for (int c = 0; c < 8; c++) {
            if (c < ((n + 1) >> 1)) {
                short8 bfr = *(const short8*)(Drowsb + (16 * n + col) * 256 + c * 32 + quad * 8);
                acc = __builtin_amdgcn_mfma_f32_16x16x32_bf16(wf[c], bfr, acc, 0, 0, 0);
            }
        }

        // ---- bias + transpose C-layout -> row layout via LDS ----
        const float bw = b[64 + 16 * n + col];
#pragma unroll
        for (int r = 0; r < 4; r++)
            buf[quad * 4 + r][col] = acc[r] + bw;

        // ---- serial triangle: 16 lanes, one batch row each ----
        if (L < 16) {
            float vl[16];
#pragma unroll
            for (int p4 = 0; p4 < 4; p4++) {
                const float4 t = *(const float4*)&buf[L][p4 * 4];
                vl[p4 * 4 + 0] = t.x; vl[p4 * 4 + 1] = t.y;
                vl[p4 * 4 + 2] = t.z; vl[p4 * 4 + 3] = t.w;
            }
            float wl[16];
#pragma unroll
            for (int q = 0; q < 16; q++) wl[q] = 0.f;
#pragma unroll
            for (int q = 0; q < 16; q++) {
                float a = vl[q];
                const int cc = (q >= 2) ? (((q - 2) >> 2) + 1) : 0;
#pragma unroll
                for (int p4 = 0; p4 < 4; p4++) {
                    if (p4 < cc) {
                        const float4 d4 = *(const float4*)&dblk[q][p4 * 4];
                        a += d4.x * wl[p4 * 4 + 0];
                        a += d4.y * wl[p4 * 4 + 1];
                        a += d4.z * wl[p4 * 4 + 2];
                        a += d4.w * wl[p4 * 4 + 3];
                    }
                }
                a *= laminv[16 * n + q];
                a = fminf(fmaxf(a, -15.f), 15.f);
                const float e = __expf(2.f * a);
                wl[q] = (e - 1.f) * __builtin_amdgcn_rcpf(e + 1.f);
            }
            // write w back (row layout) for A-frag pickup
#pragma unroll
            for (int p4 = 0; p4 < 4; p4++)
                *(float4*)&buf[L][p4 * 4] =
                    make_float4(wl[p4 * 4], wl[p4 * 4 + 1], wl[p4 * 4 + 2], wl[p4 * 4 + 3]);
        }

        // ---- fold new w block into A-frag chunk (half-chunk update) ----
        {
            const float4 wlo = *(const float4*)&buf[col][(quad & 1) * 8];
            const float4 whi = *(const float4*)&buf[col][(quad & 1) * 8 + 4];
            const short8 nf = pack8(wlo, whi);
            const int c = n >> 1;
            if ((n & 1) == 0) {
                wf[c] = (quad < 2) ? nf : zero8;   // upper half zero until n+1
            } else {
                if (quad >= 2) wf[c] = nf;         // fill upper half
            }
        }
    }

    // ---- y phase: Y[16][32] = x0@C2^T + W@D21^T + b_y ----
    floatx4 yacc0 = {0.f, 0.f, 0.f, 0.f};
    floatx4 yacc1 = {0.f, 0.f, 0.f, 0.f};
#pragma unroll
    for (int c = 0; c < 2; c++) {
        short8 b0 = *(const short8*)(C2b + col * 64 + c * 32 + quad * 8);
        short8 b1 = *(const short8*)(C2b + (16 + col) * 64 + c * 32 + quad * 8);
        yacc0 = __builtin_amdgcn_mfma_f32_16x16x32_bf16(zf[c], b0, yacc0, 0, 0, 0);
        yacc1 = __builtin_amdgcn_mfma_f32_16x16x32_bf16(zf[c], b1, yacc1, 0, 0, 0);
    }
#pragma unroll
    for (int c = 0; c < 8; c++) {
        short8 b0 = *(const short8*)(D21b + col * 256 + c * 32 + quad * 8);
        short8 b1 = *(const short8*)(D21b + (16 + col) * 256 + c * 32 + quad * 8);
        yacc0 = __builtin_amdgcn_mfma_f32_16x16x32_bf16(wf[c], b0, yacc0, 0, 0, 0);
        yacc1 = __builtin_amdgcn_mfma_f32_16x16x32_bf16(wf[c], b1, yacc1, 0, 0, 0);
    }
    const float by0 = b[320 + col];
    const float by1 = b[320 + 16 + col];
#pragma unroll
    for (int r = 0; r < 4; r++) {
        out[(row0 + quad * 4 + r) * 32 + col]      = yacc0[r] + by0;
        out[(row0 + quad * 4 + r) * 32 + 16 + col] = yacc1[r] + by1;
    }
}

// ---------------------------------------------------------------------------
extern "C" void kernel_launch(void* const* d_in, const int* in_sizes, int n_in,
                              void* d_out, int out_size, void* d_ws, size_t ws_size,
                              hipStream_t stream)
{
    const float* u    = (const float*)d_in[0];
    const float* x0   = (const float*)d_in[1];
    const float* B2   = (const float*)d_in[2];
    const float* C2   = (const float*)d_in[3];
    const float* D12  = (const float*)d_in[4];
    const float* D21  = (const float*)d_in[5];
    const float* b    = (const float*)d_in[6];
    const float* X    = (const float*)d_in[7];
    // d_in[8] = Y1 (unused in forward)
    const float* St   = (const float*)d_in[9];
    const float* Q    = (const float*)d_in[10];
    const float* Rinv = (const float*)d_in[11];
    float* out = (float*)d_out;

    // Workspace: fp32 scratch then bf16 weight copies (~513 KB total).
    float* ws     = (float*)d_ws;
    float* lT1    = ws;                 // 384*64
    float* t1     = lT1 + 384 * 64;     // 384*64
    float* lT2    = t1 + 384 * 64;      // 384*32
    float* t2     = lT2 + 384 * 32;     // 384*32
    float* laminv = t2 + 384 * 32;      // 256
    unsigned short* Drowsb = (unsigned short*)(laminv + 256); // 256*256
    unsigned short* Wvb    = Drowsb + 256 * 256;              // 256*128
    unsigned short* C2b    = Wvb + 256 * 128;                 // 32*64
    unsigned short* D21b   = C2b + 32 * 64;                   // 32*256

    ren_prep1<<<dim3(384), dim3(64), 0, stream>>>(B2, C2, D12, D21, St, Q, Rinv,
                                                  lT1, t1, lT2, t2);
    ren_prep2<<<dim3(64), dim3(320), 0, stream>>>(X, lT1, t1, lT2, t2,
                                                  Wvb, Drowsb, laminv);
    ren_prep3<<<dim3(104), dim3(256), 0, stream>>>(D12, C2, D21, Wvb, C2b, D21b);

    const int batch = in_sizes[0] / 64;            // 32768
    ren_main<<<dim3(batch / 16), dim3(64), 0, stream>>>(u, x0, b, Wvb, Drowsb,
                                                        laminv, C2b, D21b, out);
}

// Round 3
// 153.070 us; speedup vs baseline: 5.0605x; 1.0885x over previous
//
#include <hip/hip_runtime.h>
#include <hip/hip_bf16.h>

// REN forward: BATCH=32768, N_X=64, N_UNITS=256, N_Y=32, N_U=64
typedef __attribute__((ext_vector_type(8))) short short8;
typedef __attribute__((ext_vector_type(4))) float floatx4;

__device__ inline unsigned short bf16_rn(float f) {
    return (unsigned short)((__float_as_uint(f) + 0x8000u) >> 16);
}
__device__ inline short8 pack8(float4 a, float4 b) {
    short8 r;
    r[0] = (short)bf16_rn(a.x); r[1] = (short)bf16_rn(a.y);
    r[2] = (short)bf16_rn(a.z); r[3] = (short)bf16_rn(a.w);
    r[4] = (short)bf16_rn(b.x); r[5] = (short)bf16_rn(b.y);
    r[6] = (short)bf16_rn(b.z); r[7] = (short)bf16_rn(b.w);
    return r;
}

// ---------------------------------------------------------------------------
// Prep13: blocks 0..383 = old prep1 (lT1,t1,lT2,t2) with St staged in padded
// LDS; blocks 384..799 = old prep3 (bf16 copies of D12/C2/D21).
// ---------------------------------------------------------------------------
__global__ __launch_bounds__(64) void ren_prep13(
    const float* __restrict__ B2, const float* __restrict__ C2,
    const float* __restrict__ D12, const float* __restrict__ D21,
    const float* __restrict__ St, const float* __restrict__ Q,
    const float* __restrict__ Rinv,
    float* __restrict__ lT1, float* __restrict__ t1,
    float* __restrict__ lT2, float* __restrict__ t2,
    unsigned short* __restrict__ Wvb, unsigned short* __restrict__ C2b,
    unsigned short* __restrict__ D21b)
{
    const int t = threadIdx.x;
    const int blk = blockIdx.x;
    if (blk >= 384) {   // prep3 role (uniform branch)
        const int id = (blk - 384) * 64 + t;
        if (id < 16384) {
            Wvb[(id >> 6) * 128 + 64 + (id & 63)] = bf16_rn(D12[id]);
        } else if (id < 16384 + 2048) {
            C2b[id - 16384] = bf16_rn(C2[id - 16384]);
        } else if (id < 16384 + 2048 + 8192) {
            D21b[id - 18432] = bf16_rn(D21[id - 18432]);
        }
        return;
    }

    __shared__ float stl[64 * 33];  // St (64x32) padded: bank = (c+p)%32
    __shared__ float s1[64];
    __shared__ float s2[32];
#pragma unroll
    for (int j = 0; j < 32; j++) {
        const int id = j * 64 + t;
        stl[(id >> 5) * 33 + (id & 31)] = St[id];
    }
    __syncthreads();

    const int r = blk;   // 0..383
    const int c = t;     // 0..63

    float v1;
    if (r < 64) {
        float s = 0.f;
#pragma unroll
        for (int p = 0; p < 32; p++) s += stl[c * 33 + p] * C2[p * 64 + r];
        v1 = s;
    } else if (r < 320) {
        const int j = r - 64;
        float s = 0.f;
#pragma unroll
        for (int p = 0; p < 32; p++) s += stl[c * 33 + p] * D21[p * 256 + j];
        v1 = s - D12[j * 64 + c];
    } else {
        v1 = B2[(r - 320) * 64 + c];
    }
    s1[c] = v1;
    lT1[r * 64 + c] = v1;

    if (c < 32) {
        float v2;
        if (r < 64)       v2 = C2[c * 64 + r];
        else if (r < 320) v2 = D21[c * 256 + (r - 64)];
        else              v2 = 0.f;
        s2[c] = v2;
        lT2[r * 32 + c] = v2;
    }
    __syncthreads();

    float a = 0.f;
#pragma unroll
    for (int k = 0; k < 64; k++) a += s1[k] * Rinv[k * 64 + c];
    t1[r * 64 + c] = a;

    if (c < 32) {
        float bq = 0.f;
#pragma unroll
        for (int k = 0; k < 32; k++) bq += s2[k] * Q[k * 32 + c];
        t2[r * 32 + c] = bq;
    }
}

// ---------------------------------------------------------------------------
// Prep 2: one H-row per block (256 blocks x 320 threads), k-unroll 8, 4 accs.
// H[64+i][c] = sum_k X[k][64+i]X[k][c] + t1[64+i].lT1[c] - t2[64+i].lT2[c]
//            + 0.001*(64+i==c)
// Emits: Wvb cols 0..63 (C_1, bf16), Drowsb (bf16 w/ stored zeros),
//        Dtri (fp32 16x16 diagonal blocks for the triangle), laminv.
// ---------------------------------------------------------------------------
__global__ __launch_bounds__(320) void ren_prep2(
    const float* __restrict__ X,
    const float* __restrict__ lT1, const float* __restrict__ t1,
    const float* __restrict__ lT2, const float* __restrict__ t2,
    unsigned short* __restrict__ Wvb, unsigned short* __restrict__ Drowsb,
    float* __restrict__ Dtri, float* __restrict__ laminv)
{
    const int c = threadIdx.x;     // 0..319
    const int i = blockIdx.x;      // 0..255 -> H row 64+i
    const float* __restrict__ xr = X + 64 + i;

    float f0 = 0.f, f1 = 0.f, f2 = 0.f, f3 = 0.f;
    for (int k0 = 0; k0 < 384; k0 += 8) {
        float xc[8], xu[8];
#pragma unroll
        for (int kk = 0; kk < 8; kk++) {
            xc[kk] = X[(k0 + kk) * 384 + c];   // coalesced
            xu[kk] = xr[(k0 + kk) * 384];      // wave-uniform s_load
        }
        f0 += xu[0] * xc[0]; f1 += xu[1] * xc[1];
        f2 += xu[2] * xc[2]; f3 += xu[3] * xc[3];
        f0 += xu[4] * xc[4]; f1 += xu[5] * xc[5];
        f2 += xu[6] * xc[6]; f3 += xu[7] * xc[7];
    }

    const float* __restrict__ t1r = t1 + (64 + i) * 64;  // uniform
    const float* __restrict__ l1r = lT1 + c * 64;        // per-lane contiguous
#pragma unroll
    for (int m4 = 0; m4 < 16; m4++) {
        const float4 lv = *(const float4*)(l1r + m4 * 4);
        f0 += t1r[m4 * 4 + 0] * lv.x; f1 += t1r[m4 * 4 + 1] * lv.y;
        f2 += t1r[m4 * 4 + 2] * lv.z; f3 += t1r[m4 * 4 + 3] * lv.w;
    }
    const float* __restrict__ t2r = t2 + (64 + i) * 32;
    const float* __restrict__ l2r = lT2 + c * 32;
#pragma unroll
    for (int m4 = 0; m4 < 8; m4++) {
        const float4 lv = *(const float4*)(l2r + m4 * 4);
        f0 -= t2r[m4 * 4 + 0] * lv.x; f1 -= t2r[m4 * 4 + 1] * lv.y;
        f2 -= t2r[m4 * 4 + 2] * lv.z; f3 -= t2r[m4 * 4 + 3] * lv.w;
    }
    float acc = (f0 + f1) + (f2 + f3) + (((64 + i) == c) ? 0.001f : 0.f);

    if (c < 64) {
        Wvb[i * 128 + c] = bf16_rn(-acc);       // C_1 = -H_21
    } else {
        const int cb = c - 64;
        if (cb == i) laminv[i] = 2.0f / acc;
        if (i < 255) {
            const float dv = (cb <= i - 1) ? -acc : 0.f;
            Drowsb[(i + 1) * 256 + cb] = bf16_rn(dv);
            if (((i + 1) >> 4) == (cb >> 4))    // diagonal 16-block
                Dtri[((i + 1) >> 4) * 256 + ((i + 1) & 15) * 16 + (cb & 15)] = dv;
        } else {
            Drowsb[cb] = 0;                     // Drows row 0 = zeros
        }
    }
}

// ---------------------------------------------------------------------------
// Main: one wave per 16 batch rows. GEMM-shaped work on mfma_f32_16x16x32_bf16
// with ping-pong prefetched B-frags; in-block 16x16 triangle reads D from
// fp32 Dtri via wave-uniform scalar loads (no LDS staging).
// ---------------------------------------------------------------------------
__global__ __launch_bounds__(64) void ren_main(
    const float* __restrict__ u, const float* __restrict__ x0,
    const float* __restrict__ b,
    const unsigned short* __restrict__ Wvb,
    const unsigned short* __restrict__ Drowsb,
    const float* __restrict__ Dtri,
    const float* __restrict__ laminv,
    const unsigned short* __restrict__ C2b,
    const unsigned short* __restrict__ D21b,
    float* __restrict__ out)
{
    __shared__ float buf[16][20];   // v / w transpose buffer (stride 20)

    const int L = threadIdx.x;
    const int col = L & 15;
    const int quad = L >> 4;
    const int row0 = blockIdx.x * 16;

    // z A-frags: 4 K-chunks of 32 over [x0 | u] for batch row m=col
    short8 zf[4];
#pragma unroll
    for (int c = 0; c < 4; c++) {
        const float* p = (c < 2 ? x0 : u) + (row0 + col) * 64 + (c & 1) * 32 + quad * 8;
        const float4 lo = *(const float4*)p;
        const float4 hi = *(const float4*)(p + 4);
        zf[c] = pack8(lo, hi);
    }

    const short8 zero8 = {0, 0, 0, 0, 0, 0, 0, 0};
    short8 wf[8];
#pragma unroll
    for (int c = 0; c < 8; c++) wf[c] = zero8;

    // ping-pong B-frag buffers
    short8 vf[2][4], hf[2][8];
#pragma unroll
    for (int c = 0; c < 4; c++)
        vf[0][c] = *(const short8*)(Wvb + col * 128 + c * 32 + quad * 8);
#pragma unroll
    for (int c = 0; c < 8; c++) { hf[0][c] = zero8; hf[1][c] = zero8; }

#pragma unroll
    for (int n = 0; n < 16; n++) {
        const int cur = n & 1, nxt = cur ^ 1;

        // ---- prefetch next block's B-frags (latency hidden by triangle) ----
        if (n < 15) {
#pragma unroll
            for (int c = 0; c < 4; c++)
                vf[nxt][c] = *(const short8*)(Wvb + (16 * (n + 1) + col) * 128 + c * 32 + quad * 8);
#pragma unroll
            for (int c = 0; c < 8; c++)
                if (c < ((n + 2) >> 1))
                    hf[nxt][c] = *(const short8*)(Drowsb + (16 * (n + 1) + col) * 256 + c * 32 + quad * 8);
        }

        // ---- v GEMM + dense history for block n ----
        floatx4 acc = {0.f, 0.f, 0.f, 0.f};
#pragma unroll
        for (int c = 0; c < 4; c++)
            acc = __builtin_amdgcn_mfma_f32_16x16x32_bf16(zf[c], vf[cur][c], acc, 0, 0, 0);
#pragma unroll
        for (int c = 0; c < 8; c++)
            if (c < ((n + 1) >> 1))
                acc = __builtin_amdgcn_mfma_f32_16x16x32_bf16(wf[c], hf[cur][c], acc, 0, 0, 0);

        // ---- bias + transpose C-layout -> row layout via LDS ----
        const float bw = b[64 + 16 * n + col];
#pragma unroll
        for (int r = 0; r < 4; r++)
            buf[quad * 4 + r][col] = acc[r] + bw;

        // ---- serial triangle: 16 lanes, one batch row each; D via s_loads ----
        if (L < 16) {
            float vl[16];
#pragma unroll
            for (int p4 = 0; p4 < 4; p4++) {
                const float4 tv = *(const float4*)&buf[L][p4 * 4];
                vl[p4 * 4 + 0] = tv.x; vl[p4 * 4 + 1] = tv.y;
                vl[p4 * 4 + 2] = tv.z; vl[p4 * 4 + 3] = tv.w;
            }
            float wl[16];
#pragma unroll
            for (int q = 0; q < 16; q++) {
                float aa = vl[q], ab = 0.f;
                const float* __restrict__ dq = Dtri + n * 256 + q * 16;  // uniform
#pragma unroll
                for (int p = 0; p + 2 <= q; p++) {
                    const float d = dq[p];
                    if (p & 1) ab += d * wl[p];
                    else       aa += d * wl[p];
                }
                float a = (aa + ab) * laminv[16 * n + q];
                a = fminf(15.f, fmaxf(-15.f, a));
                const float e = __expf(2.f * a);
                wl[q] = (e - 1.f) * __builtin_amdgcn_rcpf(e + 1.f);
            }
#pragma unroll
            for (int p4 = 0; p4 < 4; p4++)
                *(float4*)&buf[L][p4 * 4] = make_float4(
                    wl[p4 * 4], wl[p4 * 4 + 1], wl[p4 * 4 + 2], wl[p4 * 4 + 3]);
        }

        // ---- fold new w block into A-frag chunk (half-chunk update) ----
        {
            const float4 wlo = *(const float4*)&buf[col][(quad & 1) * 8];
            const float4 whi = *(const float4*)&buf[col][(quad & 1) * 8 + 4];
            const short8 nf = pack8(wlo, whi);
            const int cc = n >> 1;
            if ((n & 1) == 0) {
                wf[cc] = (quad < 2) ? nf : zero8;   // upper K-half zero until n+1
            } else {
                if (quad >= 2) wf[cc] = nf;         // fill upper K-half
            }
        }
    }

    // ---- y phase: Y[16][32] = z@[C2|..]^T + W@D21^T + b_y ----
    floatx4 yacc0 = {0.f, 0.f, 0.f, 0.f};
    floatx4 yacc1 = {0.f, 0.f, 0.f, 0.f};
#pragma unroll
    for (int c = 0; c < 2; c++) {
        const short8 b0 = *(const short8*)(C2b + col * 64 + c * 32 + quad * 8);
        const short8 b1 = *(const short8*)(C2b + (16 + col) * 64 + c * 32 + quad * 8);
        yacc0 = __builtin_amdgcn_mfma_f32_16x16x32_bf16(zf[c], b0, yacc0, 0, 0, 0);
        yacc1 = __builtin_amdgcn_mfma_f32_16x16x32_bf16(zf[c], b1, yacc1, 0, 0, 0);
    }
#pragma unroll
    for (int c = 0; c < 8; c++) {
        const short8 b0 = *(const short8*)(D21b + col * 256 + c * 32 + quad * 8);
        const short8 b1 = *(const short8*)(D21b + (16 + col) * 256 + c * 32 + quad * 8);
        yacc0 = __builtin_amdgcn_mfma_f32_16x16x32_bf16(wf[c], b0, yacc0, 0, 0, 0);
        yacc1 = __builtin_amdgcn_mfma_f32_16x16x32_bf16(wf[c], b1, yacc1, 0, 0, 0);
    }
    const float by0 = b[320 + col];
    const float by1 = b[320 + 16 + col];
#pragma unroll
    for (int r = 0; r < 4; r++) {
        out[(row0 + quad * 4 + r) * 32 + col]      = yacc0[r] + by0;
        out[(row0 + quad * 4 + r) * 32 + 16 + col] = yacc1[r] + by1;
    }
}

// ---------------------------------------------------------------------------
extern "C" void kernel_launch(void* const* d_in, const int* in_sizes, int n_in,
                              void* d_out, int out_size, void* d_ws, size_t ws_size,
                              hipStream_t stream)
{
    const float* u    = (const float*)d_in[0];
    const float* x0   = (const float*)d_in[1];
    const float* B2   = (const float*)d_in[2];
    const float* C2   = (const float*)d_in[3];
    const float* D12  = (const float*)d_in[4];
    const float* D21  = (const float*)d_in[5];
    const float* b    = (const float*)d_in[6];
    const float* X    = (const float*)d_in[7];
    // d_in[8] = Y1 (unused in forward)
    const float* St   = (const float*)d_in[9];
    const float* Q    = (const float*)d_in[10];
    const float* Rinv = (const float*)d_in[11];
    float* out = (float*)d_out;

    // Workspace: fp32 scratch, then bf16 weight copies (~530 KB total).
    float* ws     = (float*)d_ws;
    float* lT1    = ws;                 // 384*64
    float* t1     = lT1 + 384 * 64;     // 384*64
    float* lT2    = t1 + 384 * 64;      // 384*32
    float* t2     = lT2 + 384 * 32;     // 384*32
    float* laminv = t2 + 384 * 32;      // 256
    float* Dtri   = laminv + 256;       // 16*256 fp32
    unsigned short* Drowsb = (unsigned short*)(Dtri + 16 * 256); // 256*256
    unsigned short* Wvb    = Drowsb + 256 * 256;                 // 256*128
    unsigned short* C2b    = Wvb + 256 * 128;                    // 32*64
    unsigned short* D21b   = C2b + 32 * 64;                      // 32*256

    ren_prep13<<<dim3(800), dim3(64), 0, stream>>>(B2, C2, D12, D21, St, Q, Rinv,
                                                   lT1, t1, lT2, t2, Wvb, C2b, D21b);
    ren_prep2<<<dim3(256), dim3(320), 0, stream>>>(X, lT1, t1, lT2, t2,
                                                   Wvb, Drowsb, Dtri, laminv);

    const int batch = in_sizes[0] / 64;            // 32768
    ren_main<<<dim3(batch / 16), dim3(64), 0, stream>>>(u, x0, b, Wvb, Drowsb,
                                                        Dtri, laminv, C2b, D21b, out);
}

// Round 4
// 146.272 us; speedup vs baseline: 5.2956x; 1.0465x over previous
//
#include <hip/hip_runtime.h>
#include <hip/hip_bf16.h>

// REN forward: BATCH=32768, N_X=64, N_UNITS=256, N_Y=32, N_U=64
typedef __attribute__((ext_vector_type(8))) short short8;
typedef __attribute__((ext_vector_type(4))) float floatx4;

#define MFMA16 __builtin_amdgcn_mfma_f32_16x16x32_bf16

__device__ inline unsigned short bf16_rn(float f) {
    return (unsigned short)((__float_as_uint(f) + 0x8000u) >> 16);
}
__device__ inline short8 pack8(const float* v) {
    short8 r;
#pragma unroll
    for (int j = 0; j < 8; j++) r[j] = (short)bf16_rn(v[j]);
    return r;
}

// ---------------------------------------------------------------------------
// Prep13: blocks 0..383 = lT1/t1/lT2/t2; blocks 384..799 = bf16 copies.
// The C2/D21 column a block needs is staged by 32 parallel lanes into LDS
// (was: 32 serial wave-uniform s_loads -> lgkmcnt(0) chains).
// ---------------------------------------------------------------------------
__global__ __launch_bounds__(64) void ren_prep13(
    const float* __restrict__ B2, const float* __restrict__ C2,
    const float* __restrict__ D12, const float* __restrict__ D21,
    const float* __restrict__ St, const float* __restrict__ Q,
    const float* __restrict__ Rinv,
    float* __restrict__ lT1, float* __restrict__ t1,
    float* __restrict__ lT2, float* __restrict__ t2,
    unsigned short* __restrict__ Wvb, unsigned short* __restrict__ C2b,
    unsigned short* __restrict__ D21b)
{
    const int t = threadIdx.x;
    const int blk = blockIdx.x;
    if (blk >= 384) {   // bf16-copy role (uniform branch)
        const int id = (blk - 384) * 64 + t;
        if (id < 16384) {
            Wvb[(id >> 6) * 128 + 64 + (id & 63)] = bf16_rn(D12[id]);
        } else if (id < 16384 + 2048) {
            C2b[id - 16384] = bf16_rn(C2[id - 16384]);
        } else if (id < 16384 + 2048 + 8192) {
            D21b[id - 18432] = bf16_rn(D21[id - 18432]);
        }
        return;
    }

    __shared__ float stl[64 * 33];  // St (64x32), padded
    __shared__ float colbuf[32];    // this block's C2/D21 column
    __shared__ float s1[64];

    const int r = blk;   // 0..383
    const int c = t;     // 0..63
#pragma unroll
    for (int j = 0; j < 32; j++) {
        const int id = j * 64 + t;
        stl[(id >> 5) * 33 + (id & 31)] = St[id];
    }
    if (t < 32)
        colbuf[t] = (r < 64) ? C2[t * 64 + r]
                  : (r < 320 ? D21[t * 256 + (r - 64)] : 0.f);
    __syncthreads();

    float v1;
    if (r < 64) {
        float s = 0.f;
#pragma unroll
        for (int p = 0; p < 32; p++) s += stl[c * 33 + p] * colbuf[p];
        v1 = s;
    } else if (r < 320) {
        float s = 0.f;
#pragma unroll
        for (int p = 0; p < 32; p++) s += stl[c * 33 + p] * colbuf[p];
        v1 = s - D12[(r - 64) * 64 + c];
    } else {
        v1 = B2[(r - 320) * 64 + c];
    }
    s1[c] = v1;
    lT1[r * 64 + c] = v1;
    if (c < 32) {
        const float v2 = (r < 320) ? colbuf[c] : 0.f;
        lT2[r * 32 + c] = v2;
    }
    __syncthreads();

    float a = 0.f;
#pragma unroll
    for (int k = 0; k < 64; k++) a += s1[k] * Rinv[k * 64 + c];
    t1[r * 64 + c] = a;

    if (c < 32) {
        float bq = 0.f;
#pragma unroll
        for (int k = 0; k < 32; k++) bq += colbuf[k] * Q[k * 32 + c];
        t2[r * 32 + c] = bq;
    }
}

// ---------------------------------------------------------------------------
// Prep 2: one H-row per block (256 x 320). X row 64+i staged in LDS (no
// SMEM in the k-loop); k-loop software-pipelined (A/B register buffers).
// Emits Wvb cols 0..63, Drowsb (stored zeros), Dtri fp32 (+ zeroed row 0),
// lamg[i] = 4*log2(e)/H22[i][i]  (pre-folded tanh scale).
// ---------------------------------------------------------------------------
__global__ __launch_bounds__(320) void ren_prep2(
    const float* __restrict__ X,
    const float* __restrict__ lT1, const float* __restrict__ t1,
    const float* __restrict__ lT2, const float* __restrict__ t2,
    unsigned short* __restrict__ Wvb, unsigned short* __restrict__ Drowsb,
    float* __restrict__ Dtri, float* __restrict__ lamg)
{
    __shared__ float xcol[384];
    const int c = threadIdx.x;     // 0..319
    const int i = blockIdx.x;      // 0..255 -> H row 64+i
    for (int t = c; t < 384; t += 320) xcol[t] = X[t * 384 + 64 + i];
    __syncthreads();

    float f0 = 0.f, f1 = 0.f, f2 = 0.f, f3 = 0.f;
    float ac[8], au[8], bc8[8], bu[8];
#pragma unroll
    for (int kk = 0; kk < 8; kk++) { ac[kk] = X[kk * 384 + c]; au[kk] = xcol[kk]; }
    for (int k0 = 0; k0 < 384; k0 += 16) {
#pragma unroll
        for (int kk = 0; kk < 8; kk++) {
            bc8[kk] = X[(k0 + 8 + kk) * 384 + c]; bu[kk] = xcol[k0 + 8 + kk];
        }
        f0 += au[0] * ac[0]; f1 += au[1] * ac[1];
        f2 += au[2] * ac[2]; f3 += au[3] * ac[3];
        f0 += au[4] * ac[4]; f1 += au[5] * ac[5];
        f2 += au[6] * ac[6]; f3 += au[7] * ac[7];
        if (k0 + 16 < 384) {
#pragma unroll
            for (int kk = 0; kk < 8; kk++) {
                ac[kk] = X[(k0 + 16 + kk) * 384 + c]; au[kk] = xcol[k0 + 16 + kk];
            }
        }
        f0 += bu[0] * bc8[0]; f1 += bu[1] * bc8[1];
        f2 += bu[2] * bc8[2]; f3 += bu[3] * bc8[3];
        f0 += bu[4] * bc8[4]; f1 += bu[5] * bc8[5];
        f2 += bu[6] * bc8[6]; f3 += bu[7] * bc8[7];
    }

    const float* __restrict__ t1r = t1 + (64 + i) * 64;  // uniform (one-shot)
    const float* __restrict__ l1r = lT1 + c * 64;
#pragma unroll
    for (int m4 = 0; m4 < 16; m4++) {
        const float4 lv = *(const float4*)(l1r + m4 * 4);
        f0 += t1r[m4 * 4 + 0] * lv.x; f1 += t1r[m4 * 4 + 1] * lv.y;
        f2 += t1r[m4 * 4 + 2] * lv.z; f3 += t1r[m4 * 4 + 3] * lv.w;
    }
    const float* __restrict__ t2r = t2 + (64 + i) * 32;
    const float* __restrict__ l2r = lT2 + c * 32;
#pragma unroll
    for (int m4 = 0; m4 < 8; m4++) {
        const float4 lv = *(const float4*)(l2r + m4 * 4);
        f0 -= t2r[m4 * 4 + 0] * lv.x; f1 -= t2r[m4 * 4 + 1] * lv.y;
        f2 -= t2r[m4 * 4 + 2] * lv.z; f3 -= t2r[m4 * 4 + 3] * lv.w;
    }
    float acc = (f0 + f1) + (f2 + f3) + (((64 + i) == c) ? 0.001f : 0.f);

    if (c < 64) {
        Wvb[i * 128 + c] = bf16_rn(-acc);       // C_1 = -H_21
    } else {
        const int cb = c - 64;
        if (i == 0 && cb < 16) Dtri[cb] = 0.f;  // unwritten row 0 of block 0
        if (cb == i) lamg[i] = 5.7707801635558536f / acc;  // 4*log2e/lam /? (=2*log2e/(acc/2))
        if (i < 255) {
            const float dv = (cb <= i - 1) ? -acc : 0.f;
            Drowsb[(i + 1) * 256 + cb] = bf16_rn(dv);
            if (((i + 1) >> 4) == (cb >> 4))
                Dtri[((i + 1) >> 4) * 256 + ((i + 1) & 15) * 16 + (cb & 15)] = dv;
        } else {
            Drowsb[cb] = 0;
        }
    }
}

// ---------------------------------------------------------------------------
// Main: one wave per 16 batch rows. MFMA GEMMs with register ping-pong
// prefetch (vector loads only); triangle redundant on all 64 lanes with D
// broadcast from LDS (fp32, prefetched one iteration ahead); lam scale and
// b_w staged in LDS; w folds into A-frags straight from registers.
// ---------------------------------------------------------------------------
__global__ __launch_bounds__(64) void ren_main(
    const float* __restrict__ u, const float* __restrict__ x0,
    const float* __restrict__ b,
    const unsigned short* __restrict__ Wvb,
    const unsigned short* __restrict__ Drowsb,
    const float* __restrict__ Dtri,
    const float* __restrict__ lamg,
    const unsigned short* __restrict__ C2b,
    const unsigned short* __restrict__ D21b,
    float* __restrict__ out)
{
    __shared__ float buf[16][20];   // acc transpose (stride 20 -> 2-way max)
    __shared__ float dblk[256];     // current 16x16 D tile [q*16+p]
    __shared__ float lamsh[256];
    __shared__ float bsh[256];

    const int L = threadIdx.x;
    const int col = L & 15;
    const int quad = L >> 4;
    const int row0 = blockIdx.x * 16;

#pragma unroll
    for (int j = 0; j < 4; j++) {
        lamsh[j * 64 + L] = lamg[j * 64 + L];
        bsh[j * 64 + L]   = b[64 + j * 64 + L];
    }

    // z A-frags: 4 K-chunks of 32 over [x0 | u], batch row m=col
    short8 zf[4];
#pragma unroll
    for (int c = 0; c < 4; c++) {
        const float* p = (c < 2 ? x0 : u) + (long)(row0 + col) * 64 + (c & 1) * 32 + quad * 8;
        float t[8];
        *(float4*)&t[0] = *(const float4*)p;
        *(float4*)&t[4] = *(const float4*)(p + 4);
        zf[c] = pack8(t);
    }

    const short8 zero8 = {0, 0, 0, 0, 0, 0, 0, 0};
    short8 wf[8];
#pragma unroll
    for (int c = 0; c < 8; c++) wf[c] = zero8;

    short8 vf[2][4], hf[2][8], yc[4];
    float4 dt = *(const float4*)(Dtri + 4 * L);   // D tile for n=0
#pragma unroll
    for (int c = 0; c < 4; c++)
        vf[0][c] = *(const short8*)(Wvb + col * 128 + c * 32 + quad * 8);
#pragma unroll
    for (int c = 0; c < 8; c++) { hf[0][c] = zero8; hf[1][c] = zero8; }

#pragma unroll
    for (int n = 0; n < 16; n++) {
        const int cur = n & 1, nxt = cur ^ 1;

        *(float4*)&dblk[4 * L] = dt;   // D tile for this n (prefetched)

        // ---- prefetch next iteration's operands (vector loads, vmcnt) ----
        if (n < 15) {
            dt = *(const float4*)(Dtri + (n + 1) * 256 + 4 * L);
#pragma unroll
            for (int c = 0; c < 4; c++)
                vf[nxt][c] = *(const short8*)(Wvb + (16 * (n + 1) + col) * 128 + c * 32 + quad * 8);
#pragma unroll
            for (int c = 0; c < 8; c++)
                if (c < ((n + 2) >> 1))
                    hf[nxt][c] = *(const short8*)(Drowsb + (16 * (n + 1) + col) * 256 + c * 32 + quad * 8);
        } else {
            yc[0] = *(const short8*)(C2b + col * 64 + quad * 8);
            yc[1] = *(const short8*)(C2b + col * 64 + 32 + quad * 8);
            yc[2] = *(const short8*)(C2b + (16 + col) * 64 + quad * 8);
            yc[3] = *(const short8*)(C2b + (16 + col) * 64 + 32 + quad * 8);
        }

        // ---- v GEMM + dense history (2 independent accumulator chains) ----
        floatx4 acc0 = {0.f, 0.f, 0.f, 0.f}, acc1 = {0.f, 0.f, 0.f, 0.f};
        acc0 = MFMA16(zf[0], vf[cur][0], acc0, 0, 0, 0);
        acc1 = MFMA16(zf[1], vf[cur][1], acc1, 0, 0, 0);
        acc0 = MFMA16(zf[2], vf[cur][2], acc0, 0, 0, 0);
        acc1 = MFMA16(zf[3], vf[cur][3], acc1, 0, 0, 0);
#pragma unroll
        for (int c = 0; c < 8; c++)
            if (c < ((n + 1) >> 1)) {
                if (c & 1) acc1 = MFMA16(wf[c], hf[cur][c], acc1, 0, 0, 0);
                else       acc0 = MFMA16(wf[c], hf[cur][c], acc0, 0, 0, 0);
            }

        // ---- bias + transpose C-layout -> row layout via LDS ----
        const float bwv = bsh[16 * n + col];
#pragma unroll
        for (int r = 0; r < 4; r++)
            buf[quad * 4 + r][col] = acc0[r] + acc1[r] + bwv;

        float vl[16], lmv[16];
#pragma unroll
        for (int p4 = 0; p4 < 4; p4++) {
            *(float4*)&vl[p4 * 4]  = *(const float4*)&buf[col][p4 * 4];
            *(float4*)&lmv[p4 * 4] = *(const float4*)&lamsh[16 * n + p4 * 4];
        }

        // ---- triangle, redundant on all 64 lanes (row = col) ----
        float wl[16];
#pragma unroll
        for (int q = 0; q < 16; q++) wl[q] = 0.f;
#pragma unroll
        for (int q = 0; q < 16; q++) {
            float aa = vl[q], ab = 0.f;
            const int nb = (q >= 2) ? ((q + 2) >> 2) : 0;
#pragma unroll
            for (int p4 = 0; p4 < nb; p4++) {
                const float4 d4 = *(const float4*)&dblk[q * 16 + p4 * 4];  // broadcast
                aa += d4.x * wl[p4 * 4 + 0];
                ab += d4.y * wl[p4 * 4 + 1];
                aa += d4.z * wl[p4 * 4 + 2];
                ab += d4.w * wl[p4 * 4 + 3];
            }
            float tt = (aa + ab) * lmv[q];
            tt = fminf(44.f, fmaxf(-44.f, tt));
            const float e = __builtin_amdgcn_exp2f(tt);     // e^(2 t/lam)
            wl[q] = 1.f - 2.f * __builtin_amdgcn_rcpf(e + 1.f);
        }

        // ---- fold w block into A-frag chunk straight from registers ----
        {
            const short8 nf = pack8(&wl[(quad & 1) * 8]);
            const int cc = n >> 1;
            if ((n & 1) == 0) wf[cc] = (quad < 2) ? nf : zero8;
            else if (quad >= 2) wf[cc] = nf;
        }
    }

    // ---- y phase: Y[16][32] = x@C2^T + W@D21^T + b_y ----
    floatx4 y0 = {0.f, 0.f, 0.f, 0.f}, y1 = {0.f, 0.f, 0.f, 0.f};
    y0 = MFMA16(zf[0], yc[0], y0, 0, 0, 0);
    y1 = MFMA16(zf[0], yc[2], y1, 0, 0, 0);
    y0 = MFMA16(zf[1], yc[1], y0, 0, 0, 0);
    y1 = MFMA16(zf[1], yc[3], y1, 0, 0, 0);
#pragma unroll
    for (int c = 0; c < 8; c++) {
        const short8 b0 = *(const short8*)(D21b + col * 256 + c * 32 + quad * 8);
        const short8 b1 = *(const short8*)(D21b + (16 + col) * 256 + c * 32 + quad * 8);
        y0 = MFMA16(wf[c], b0, y0, 0, 0, 0);
        y1 = MFMA16(wf[c], b1, y1, 0, 0, 0);
    }
    const float by0 = b[320 + col];
    const float by1 = b[336 + col];
#pragma unroll
    for (int r = 0; r < 4; r++) {
        out[(long)(row0 + quad * 4 + r) * 32 + col]      = y0[r] + by0;
        out[(long)(row0 + quad * 4 + r) * 32 + 16 + col] = y1[r] + by1;
    }
}

// ---------------------------------------------------------------------------
extern "C" void kernel_launch(void* const* d_in, const int* in_sizes, int n_in,
                              void* d_out, int out_size, void* d_ws, size_t ws_size,
                              hipStream_t stream)
{
    const float* u    = (const float*)d_in[0];
    const float* x0   = (const float*)d_in[1];
    const float* B2   = (const float*)d_in[2];
    const float* C2   = (const float*)d_in[3];
    const float* D12  = (const float*)d_in[4];
    const float* D21  = (const float*)d_in[5];
    const float* b    = (const float*)d_in[6];
    const float* X    = (const float*)d_in[7];
    // d_in[8] = Y1 (unused in forward)
    const float* St   = (const float*)d_in[9];
    const float* Q    = (const float*)d_in[10];
    const float* Rinv = (const float*)d_in[11];
    float* out = (float*)d_out;

    float* ws     = (float*)d_ws;
    float* lT1    = ws;                 // 384*64
    float* t1     = lT1 + 384 * 64;     // 384*64
    float* lT2    = t1 + 384 * 64;      // 384*32
    float* t2     = lT2 + 384 * 32;     // 384*32
    float* lamg   = t2 + 384 * 32;      // 256
    float* Dtri   = lamg + 256;         // 16*256 fp32
    unsigned short* Drowsb = (unsigned short*)(Dtri + 16 * 256); // 256*256
    unsigned short* Wvb    = Drowsb + 256 * 256;                 // 256*128
    unsigned short* C2b    = Wvb + 256 * 128;                    // 32*64
    unsigned short* D21b   = C2b + 32 * 64;                      // 32*256

    ren_prep13<<<dim3(800), dim3(64), 0, stream>>>(B2, C2, D12, D21, St, Q, Rinv,
                                                   lT1, t1, lT2, t2, Wvb, C2b, D21b);
    ren_prep2<<<dim3(256), dim3(320), 0, stream>>>(X, lT1, t1, lT2, t2,
                                                   Wvb, Drowsb, Dtri, lamg);

    const int batch = in_sizes[0] / 64;            // 32768
    ren_main<<<dim3(batch / 16), dim3(64), 0, stream>>>(u, x0, b, Wvb, Drowsb,
                                                        Dtri, lamg, C2b, D21b, out);
}

// Round 5
// 142.150 us; speedup vs baseline: 5.4492x; 1.0290x over previous
//
#include <hip/hip_runtime.h>
#include <hip/hip_bf16.h>

// REN forward: BATCH=32768, N_X=64, N_UNITS=256, N_Y=32, N_U=64
typedef __attribute__((ext_vector_type(8))) short short8;
typedef __attribute__((ext_vector_type(4))) float floatx4;

#define MFMA16 __builtin_amdgcn_mfma_f32_16x16x32_bf16

__device__ inline unsigned short bf16_rn(float f) {
    return (unsigned short)((__float_as_uint(f) + 0x8000u) >> 16);
}
__device__ inline short8 pack8(const float* v) {
    short8 r;
#pragma unroll
    for (int j = 0; j < 8; j++) r[j] = (short)bf16_rn(v[j]);
    return r;
}

// ---------------------------------------------------------------------------
// Prep13: blocks 0..383 = lT1/t1/lT2/t2 (St staged in padded LDS, C2/D21
// column staged by 32 parallel lanes); blocks 384..799 = bf16 copies.
// ---------------------------------------------------------------------------
__global__ __launch_bounds__(64) void ren_prep13(
    const float* __restrict__ B2, const float* __restrict__ C2,
    const float* __restrict__ D12, const float* __restrict__ D21,
    const float* __restrict__ St, const float* __restrict__ Q,
    const float* __restrict__ Rinv,
    float* __restrict__ lT1, float* __restrict__ t1,
    float* __restrict__ lT2, float* __restrict__ t2,
    unsigned short* __restrict__ Wvb, unsigned short* __restrict__ C2b,
    unsigned short* __restrict__ D21b)
{
    const int t = threadIdx.x;
    const int blk = blockIdx.x;
    if (blk >= 384) {   // bf16-copy role (uniform branch)
        const int id = (blk - 384) * 64 + t;
        if (id < 16384) {
            Wvb[(id >> 6) * 128 + 64 + (id & 63)] = bf16_rn(D12[id]);
        } else if (id < 16384 + 2048) {
            C2b[id - 16384] = bf16_rn(C2[id - 16384]);
        } else if (id < 16384 + 2048 + 8192) {
            D21b[id - 18432] = bf16_rn(D21[id - 18432]);
        }
        return;
    }

    __shared__ float stl[64 * 33];  // St (64x32), padded
    __shared__ float colbuf[32];    // this block's C2/D21 column
    __shared__ float s1[64];

    const int r = blk;   // 0..383
    const int c = t;     // 0..63
#pragma unroll
    for (int j = 0; j < 32; j++) {
        const int id = j * 64 + t;
        stl[(id >> 5) * 33 + (id & 31)] = St[id];
    }
    if (t < 32)
        colbuf[t] = (r < 64) ? C2[t * 64 + r]
                  : (r < 320 ? D21[t * 256 + (r - 64)] : 0.f);
    __syncthreads();

    float v1;
    if (r < 64) {
        float s = 0.f;
#pragma unroll
        for (int p = 0; p < 32; p++) s += stl[c * 33 + p] * colbuf[p];
        v1 = s;
    } else if (r < 320) {
        float s = 0.f;
#pragma unroll
        for (int p = 0; p < 32; p++) s += stl[c * 33 + p] * colbuf[p];
        v1 = s - D12[(r - 64) * 64 + c];
    } else {
        v1 = B2[(r - 320) * 64 + c];
    }
    s1[c] = v1;
    lT1[r * 64 + c] = v1;
    if (c < 32) {
        const float v2 = (r < 320) ? colbuf[c] : 0.f;
        lT2[r * 32 + c] = v2;
    }
    __syncthreads();

    float a = 0.f;
#pragma unroll
    for (int k = 0; k < 64; k++) a += s1[k] * Rinv[k * 64 + c];
    t1[r * 64 + c] = a;

    if (c < 32) {
        float bq = 0.f;
#pragma unroll
        for (int k = 0; k < 32; k++) bq += colbuf[k] * Q[k * 32 + c];
        t2[r * 32 + c] = bq;
    }
}

// ---------------------------------------------------------------------------
// Prep 2: one H-row per block (256 x 320), LDS-staged X column, pipelined
// k-loop. Emits Wvb cols 0..63 (bf16), Drowsb (bf16, stored zeros),
// Dpair (fp32 pair-interleaved diagonal 16x16 blocks:
//   Dpair[n*256 + (q>>1)*32 + p*2 + (q&1)] = D[16n+q][16n+p]),
// lamg[i] = 2*log2(e) * 2/H22[i][i]  (pre-folded tanh scale).
// ---------------------------------------------------------------------------
__global__ __launch_bounds__(320) void ren_prep2(
    const float* __restrict__ X,
    const float* __restrict__ lT1, const float* __restrict__ t1,
    const float* __restrict__ lT2, const float* __restrict__ t2,
    unsigned short* __restrict__ Wvb, unsigned short* __restrict__ Drowsb,
    float* __restrict__ Dpair, float* __restrict__ lamg)
{
    __shared__ float xcol[384];
    const int c = threadIdx.x;     // 0..319
    const int i = blockIdx.x;      // 0..255 -> H row 64+i
    for (int t = c; t < 384; t += 320) xcol[t] = X[t * 384 + 64 + i];
    __syncthreads();

    float f0 = 0.f, f1 = 0.f, f2 = 0.f, f3 = 0.f;
    float ac[8], au[8], bc8[8], bu[8];
#pragma unroll
    for (int kk = 0; kk < 8; kk++) { ac[kk] = X[kk * 384 + c]; au[kk] = xcol[kk]; }
    for (int k0 = 0; k0 < 384; k0 += 16) {
#pragma unroll
        for (int kk = 0; kk < 8; kk++) {
            bc8[kk] = X[(k0 + 8 + kk) * 384 + c]; bu[kk] = xcol[k0 + 8 + kk];
        }
        f0 += au[0] * ac[0]; f1 += au[1] * ac[1];
        f2 += au[2] * ac[2]; f3 += au[3] * ac[3];
        f0 += au[4] * ac[4]; f1 += au[5] * ac[5];
        f2 += au[6] * ac[6]; f3 += au[7] * ac[7];
        if (k0 + 16 < 384) {
#pragma unroll
            for (int kk = 0; kk < 8; kk++) {
                ac[kk] = X[(k0 + 16 + kk) * 384 + c]; au[kk] = xcol[k0 + 16 + kk];
            }
        }
        f0 += bu[0] * bc8[0]; f1 += bu[1] * bc8[1];
        f2 += bu[2] * bc8[2]; f3 += bu[3] * bc8[3];
        f0 += bu[4] * bc8[4]; f1 += bu[5] * bc8[5];
        f2 += bu[6] * bc8[6]; f3 += bu[7] * bc8[7];
    }

    const float* __restrict__ t1r = t1 + (64 + i) * 64;
    const float* __restrict__ l1r = lT1 + c * 64;
#pragma unroll
    for (int m4 = 0; m4 < 16; m4++) {
        const float4 lv = *(const float4*)(l1r + m4 * 4);
        f0 += t1r[m4 * 4 + 0] * lv.x; f1 += t1r[m4 * 4 + 1] * lv.y;
        f2 += t1r[m4 * 4 + 2] * lv.z; f3 += t1r[m4 * 4 + 3] * lv.w;
    }
    const float* __restrict__ t2r = t2 + (64 + i) * 32;
    const float* __restrict__ l2r = lT2 + c * 32;
#pragma unroll
    for (int m4 = 0; m4 < 8; m4++) {
        const float4 lv = *(const float4*)(l2r + m4 * 4);
        f0 -= t2r[m4 * 4 + 0] * lv.x; f1 -= t2r[m4 * 4 + 1] * lv.y;
        f2 -= t2r[m4 * 4 + 2] * lv.z; f3 -= t2r[m4 * 4 + 3] * lv.w;
    }
    float acc = (f0 + f1) + (f2 + f3) + (((64 + i) == c) ? 0.001f : 0.f);

    if (c < 64) {
        Wvb[i * 128 + c] = bf16_rn(-acc);       // C_1 = -H_21
    } else {
        const int cb = c - 64;
        if (cb == i) lamg[i] = 5.7707801635558536f / acc;  // (2*log2e)*2/H22ii
        if (i < 255) {
            const float dv = (cb <= i - 1) ? -acc : 0.f;
            Drowsb[(i + 1) * 256 + cb] = bf16_rn(dv);
            const int row = i + 1;
            if ((row >> 4) == (cb >> 4)) {      // diagonal 16-block, pair layout
                const int q = row & 15, p = cb & 15;
                Dpair[(row >> 4) * 256 + (q >> 1) * 32 + p * 2 + (q & 1)] = dv;
            }
        } else {
            Drowsb[cb] = 0;
        }
    }
}

// ---------------------------------------------------------------------------
// Main: one wave per 16 batch rows. MFMA GEMMs with register ping-pong
// prefetch; triangle processed in PAIRS (w_i independent of w_{i-1}:
// D_11 is strictly-lower with k=-1) -> half the serial chain, 2-lane ILP.
// D pair-tile broadcast from LDS, prefetched one iteration ahead.
// ---------------------------------------------------------------------------
__global__ __launch_bounds__(64) void ren_main(
    const float* __restrict__ u, const float* __restrict__ x0,
    const float* __restrict__ b,
    const unsigned short* __restrict__ Wvb,
    const unsigned short* __restrict__ Drowsb,
    const float* __restrict__ Dpair,
    const float* __restrict__ lamg,
    const unsigned short* __restrict__ C2b,
    const unsigned short* __restrict__ D21b,
    float* __restrict__ out)
{
    __shared__ float buf[16][20];   // acc transpose (stride 20 -> 2-way max)
    __shared__ float dblk[256];     // current pair-interleaved 16x16 D tile
    __shared__ float lamsh[256];
    __shared__ float bsh[256];

    const int L = threadIdx.x;
    const int col = L & 15;
    const int quad = L >> 4;
    const int row0 = blockIdx.x * 16;

#pragma unroll
    for (int j = 0; j < 4; j++) {
        lamsh[j * 64 + L] = lamg[j * 64 + L];
        bsh[j * 64 + L]   = b[64 + j * 64 + L];
    }

    // z A-frags: 4 K-chunks of 32 over [x0 | u], batch row m=col
    short8 zf[4];
#pragma unroll
    for (int c = 0; c < 4; c++) {
        const float* p = (c < 2 ? x0 : u) + (long)(row0 + col) * 64 + (c & 1) * 32 + quad * 8;
        float t[8];
        *(float4*)&t[0] = *(const float4*)p;
        *(float4*)&t[4] = *(const float4*)(p + 4);
        zf[c] = pack8(t);
    }

    const short8 zero8 = {0, 0, 0, 0, 0, 0, 0, 0};
    short8 wf[8];
#pragma unroll
    for (int c = 0; c < 8; c++) wf[c] = zero8;

    short8 vf[2][4], hf[2][8], yc[4];
    float4 dt = *(const float4*)(Dpair + 4 * L);   // D tile for n=0
#pragma unroll
    for (int c = 0; c < 4; c++)
        vf[0][c] = *(const short8*)(Wvb + col * 128 + c * 32 + quad * 8);
#pragma unroll
    for (int c = 0; c < 8; c++) { hf[0][c] = zero8; hf[1][c] = zero8; }

#pragma unroll
    for (int n = 0; n < 16; n++) {
        const int cur = n & 1, nxt = cur ^ 1;

        *(float4*)&dblk[4 * L] = dt;   // D pair-tile for this n (prefetched)

        // ---- prefetch next iteration's operands ----
        if (n < 15) {
            dt = *(const float4*)(Dpair + (n + 1) * 256 + 4 * L);
#pragma unroll
            for (int c = 0; c < 4; c++)
                vf[nxt][c] = *(const short8*)(Wvb + (16 * (n + 1) + col) * 128 + c * 32 + quad * 8);
#pragma unroll
            for (int c = 0; c < 8; c++)
                if (c < ((n + 2) >> 1))
                    hf[nxt][c] = *(const short8*)(Drowsb + (16 * (n + 1) + col) * 256 + c * 32 + quad * 8);
        } else {
            yc[0] = *(const short8*)(C2b + col * 64 + quad * 8);
            yc[1] = *(const short8*)(C2b + col * 64 + 32 + quad * 8);
            yc[2] = *(const short8*)(C2b + (16 + col) * 64 + quad * 8);
            yc[3] = *(const short8*)(C2b + (16 + col) * 64 + 32 + quad * 8);
        }

        // ---- v GEMM + dense history (2 independent accumulator chains) ----
        floatx4 acc0 = {0.f, 0.f, 0.f, 0.f}, acc1 = {0.f, 0.f, 0.f, 0.f};
        acc0 = MFMA16(zf[0], vf[cur][0], acc0, 0, 0, 0);
        acc1 = MFMA16(zf[1], vf[cur][1], acc1, 0, 0, 0);
        acc0 = MFMA16(zf[2], vf[cur][2], acc0, 0, 0, 0);
        acc1 = MFMA16(zf[3], vf[cur][3], acc1, 0, 0, 0);
#pragma unroll
        for (int c = 0; c < 8; c++)
            if (c < ((n + 1) >> 1)) {
                if (c & 1) acc1 = MFMA16(wf[c], hf[cur][c], acc1, 0, 0, 0);
                else       acc0 = MFMA16(wf[c], hf[cur][c], acc0, 0, 0, 0);
            }

        // ---- bias + transpose C-layout -> row layout via LDS ----
        const float bwv = bsh[16 * n + col];
#pragma unroll
        for (int r = 0; r < 4; r++)
            buf[quad * 4 + r][col] = acc0[r] + acc1[r] + bwv;

        float vl[16];
#pragma unroll
        for (int p4 = 0; p4 < 4; p4++)
            *(float4*)&vl[p4 * 4] = *(const float4*)&buf[col][p4 * 4];

        // ---- triangle in pairs: w_{2t},w_{2t+1} depend only on pairs < t ----
        float wl[16];
#pragma unroll
        for (int t = 0; t < 8; t++) {
            float ax = vl[2 * t], ay = vl[2 * t + 1];
#pragma unroll
            for (int p4 = 0; p4 < t; p4++) {
                const float4 d4 = *(const float4*)&dblk[t * 32 + p4 * 4];  // broadcast
                ax = fmaf(d4.x, wl[2 * p4],     ax);
                ay = fmaf(d4.y, wl[2 * p4],     ay);
                ax = fmaf(d4.z, wl[2 * p4 + 1], ax);
                ay = fmaf(d4.w, wl[2 * p4 + 1], ay);
            }
            const float2 lm = *(const float2*)&lamsh[16 * n + 2 * t];
            // tanh(x) = 1 - 2/(exp2(x*2log2e)+1); exp2 saturation is benign
            const float e0 = __builtin_amdgcn_exp2f(ax * lm.x);
            const float e1 = __builtin_amdgcn_exp2f(ay * lm.y);
            wl[2 * t]     = 1.f - 2.f * __builtin_amdgcn_rcpf(e0 + 1.f);
            wl[2 * t + 1] = 1.f - 2.f * __builtin_amdgcn_rcpf(e1 + 1.f);
        }

        // ---- fold w block into A-frag chunk straight from registers ----
        {
            const short8 nf = pack8(&wl[(quad & 1) * 8]);
            const int cc = n >> 1;
            if ((n & 1) == 0) wf[cc] = (quad < 2) ? nf : zero8;
            else if (quad >= 2) wf[cc] = nf;
        }
    }

    // ---- y phase: Y[16][32] = x@C2^T + W@D21^T + b_y ----
    floatx4 y0 = {0.f, 0.f, 0.f, 0.f}, y1 = {0.f, 0.f, 0.f, 0.f};
    y0 = MFMA16(zf[0], yc[0], y0, 0, 0, 0);
    y1 = MFMA16(zf[0], yc[2], y1, 0, 0, 0);
    y0 = MFMA16(zf[1], yc[1], y0, 0, 0, 0);
    y1 = MFMA16(zf[1], yc[3], y1, 0, 0, 0);
#pragma unroll
    for (int c = 0; c < 8; c++) {
        const short8 b0 = *(const short8*)(D21b + col * 256 + c * 32 + quad * 8);
        const short8 b1 = *(const short8*)(D21b + (16 + col) * 256 + c * 32 + quad * 8);
        y0 = MFMA16(wf[c], b0, y0, 0, 0, 0);
        y1 = MFMA16(wf[c], b1, y1, 0, 0, 0);
    }
    const float by0 = b[320 + col];
    const float by1 = b[336 + col];
#pragma unroll
    for (int r = 0; r < 4; r++) {
        out[(long)(row0 + quad * 4 + r) * 32 + col]      = y0[r] + by0;
        out[(long)(row0 + quad * 4 + r) * 32 + 16 + col] = y1[r] + by1;
    }
}

// ---------------------------------------------------------------------------
extern "C" void kernel_launch(void* const* d_in, const int* in_sizes, int n_in,
                              void* d_out, int out_size, void* d_ws, size_t ws_size,
                              hipStream_t stream)
{
    const float* u    = (const float*)d_in[0];
    const float* x0   = (const float*)d_in[1];
    const float* B2   = (const float*)d_in[2];
    const float* C2   = (const float*)d_in[3];
    const float* D12  = (const float*)d_in[4];
    const float* D21  = (const float*)d_in[5];
    const float* b    = (const float*)d_in[6];
    const float* X    = (const float*)d_in[7];
    // d_in[8] = Y1 (unused in forward)
    const float* St   = (const float*)d_in[9];
    const float* Q    = (const float*)d_in[10];
    const float* Rinv = (const float*)d_in[11];
    float* out = (float*)d_out;

    float* ws     = (float*)d_ws;
    float* lT1    = ws;                 // 384*64
    float* t1     = lT1 + 384 * 64;     // 384*64
    float* lT2    = t1 + 384 * 64;      // 384*32
    float* t2     = lT2 + 384 * 32;     // 384*32
    float* lamg   = t2 + 384 * 32;      // 256
    float* Dpair  = lamg + 256;         // 16*256 fp32 (pair-interleaved)
    unsigned short* Drowsb = (unsigned short*)(Dpair + 16 * 256); // 256*256
    unsigned short* Wvb    = Drowsb + 256 * 256;                  // 256*128
    unsigned short* C2b    = Wvb + 256 * 128;                     // 32*64
    unsigned short* D21b   = C2b + 32 * 64;                       // 32*256

    ren_prep13<<<dim3(800), dim3(64), 0, stream>>>(B2, C2, D12, D21, St, Q, Rinv,
                                                   lT1, t1, lT2, t2, Wvb, C2b, D21b);
    ren_prep2<<<dim3(256), dim3(320), 0, stream>>>(X, lT1, t1, lT2, t2,
                                                   Wvb, Drowsb, Dpair, lamg);

    const int batch = in_sizes[0] / 64;            // 32768
    ren_main<<<dim3(batch / 16), dim3(64), 0, stream>>>(u, x0, b, Wvb, Drowsb,
                                                        Dpair, lamg, C2b, D21b, out);
}